// Round 1
// 675.922 us; speedup vs baseline: 1.0075x; 1.0075x over previous
//
#include <hip/hip_runtime.h>
#include <float.h>

#define CLS 32000
#define NVEC (CLS / 4)   // 8000 float4 per row
#define BLOCK 256

// Zero the scalar output (harness re-poisons d_out before every timed launch).
__global__ void zero_kernel(float* out) {
    if (threadIdx.x == 0) out[0] = 0.0f;
}

// Online-softmax merge of two (max, sumexp, argmax-index) states.
// Tie-break on equal max: smaller index (matches jnp.argmax first-occurrence).
__device__ __forceinline__ void merge_state(float& m, float& s, int& idx,
                                            float om, float os, int oi) {
    float M = fmaxf(m, om);
    float S = s * __expf(m - M) + os * __expf(om - M);
    int I;
    if (m > om)      I = idx;
    else if (om > m) I = oi;
    else             I = (idx < oi) ? idx : oi;
    m = M; s = S; idx = I;
}

// Branchless per-float4 online softmax + argmax update.
// Chunk max/argmax via cndmask tree (>= keeps the earlier index on ties,
// and within a chunk the left operand always has the smaller index).
// One rescale-exp per chunk instead of per element; no divergent branches,
// so the compiler can if-convert, unroll, and keep loads in flight.
__device__ __forceinline__ void proc4(float4 v, int i4,
                                      float& m, float& s, int& idx) {
    const int b = i4 * 4;
    const bool gxy = (v.x >= v.y);
    const float m01 = gxy ? v.x : v.y;
    const int   i01 = gxy ? b : b + 1;
    const bool gzw = (v.z >= v.w);
    const float m23 = gzw ? v.z : v.w;
    const int   i23 = gzw ? b + 2 : b + 3;
    const bool gc  = (m01 >= m23);
    const float cm = gc ? m01 : m23;
    const int   ci = gc ? i01 : i23;

    const float nm = fmaxf(m, cm);
    idx = (cm > m) ? ci : idx;     // strict >: running state is earlier => wins ties

    const float e0 = __expf(v.x - nm);
    const float e1 = __expf(v.y - nm);
    const float e2 = __expf(v.z - nm);
    const float e3 = __expf(v.w - nm);
    s = s * __expf(m - nm) + ((e0 + e1) + (e2 + e3));
    m = nm;
}

__global__ __launch_bounds__(BLOCK) void focal_loss_kernel(
    const float* __restrict__ input,    // [N, CLS] fp32
    const int*   __restrict__ target,   // [N] (int32: jax default x64-disabled)
    const float* __restrict__ weight,   // [CLS]
    const float* __restrict__ gammap,   // [1]
    float* __restrict__ out)            // [1]
{
    const int row = blockIdx.x;
    const size_t base = (size_t)row * CLS;
    const float4* __restrict__ rp4 = (const float4*)(input + base);
    const int tid = threadIdx.x;

    // Two independent online-softmax states for ILP across the unroll-by-2.
    float mA = -FLT_MAX, sA = 0.0f; int iA = 0x7fffffff;
    float mB = -FLT_MAX, sB = 0.0f; int iB = 0x7fffffff;

    int i = tid;
    // Main loop: both loads issue before any processing; body is branchless.
    while (i + BLOCK < NVEC) {
        const float4 a = rp4[i];
        const float4 b = rp4[i + BLOCK];
        proc4(a, i,          mA, sA, iA);
        proc4(b, i + BLOCK,  mB, sB, iB);
        i += 2 * BLOCK;
    }
    // At most one float4 remains per thread (loop exits when i+BLOCK >= NVEC).
    if (i < NVEC) proc4(rp4[i], i, mA, sA, iA);

    merge_state(mA, sA, iA, mB, sB, iB);
    float m = mA, s = sA; int idx = iA;

    // Wave(64)-level reduce via shfl_down.
    for (int off = 32; off > 0; off >>= 1) {
        float om = __shfl_down(m, off);
        float os = __shfl_down(s, off);
        int   oi = __shfl_down(idx, off);
        merge_state(m, s, idx, om, os, oi);
    }

    // Cross-wave combine (4 waves per block).
    __shared__ float sm[BLOCK / 64];
    __shared__ float ss[BLOCK / 64];
    __shared__ int   si[BLOCK / 64];
    const int wave = tid >> 6;
    if ((tid & 63) == 0) { sm[wave] = m; ss[wave] = s; si[wave] = idx; }
    __syncthreads();

    if (tid == 0) {
        for (int w = 1; w < BLOCK / 64; ++w)
            merge_state(m, s, idx, sm[w], ss[w], si[w]);

        const int   t  = target[row];
        const float xt = input[base + (size_t)t];
        const float logp_t = xt - m - __logf(s);   // log p_target
        const float p_t    = __expf(logp_t);
        const float g      = gammap[0];
        const float w      = weight[idx];          // weight[argmax(input_row)]
        const float loss   = w * __powf(1.0f - p_t, g) * (-logp_t);
        atomicAdd(out, loss);
    }
}

extern "C" void kernel_launch(void* const* d_in, const int* in_sizes, int n_in,
                              void* d_out, int out_size, void* d_ws, size_t ws_size,
                              hipStream_t stream) {
    const float* input  = (const float*)d_in[0];
    const int*   target = (const int*)  d_in[1];
    const float* weight = (const float*)d_in[2];
    const float* gammap = (const float*)d_in[3];
    float* out = (float*)d_out;

    const int N = in_sizes[0] / CLS;   // 4096

    zero_kernel<<<1, 64, 0, stream>>>(out);
    focal_loss_kernel<<<N, BLOCK, 0, stream>>>(input, target, weight, gammap, out);
}

// Round 3
// 668.077 us; speedup vs baseline: 1.0193x; 1.0117x over previous
//
#include <hip/hip_runtime.h>
#include <float.h>

#define CLS 32000
#define NVEC (CLS / 4)   // 8000 float4 per row
#define BLOCK 256

// Online-softmax merge of two (max, sumexp, argmax-index) states.
// Tie-break on equal max: smaller index (matches jnp.argmax first-occurrence).
__device__ __forceinline__ void merge_state(float& m, float& s, int& idx,
                                            float om, float os, int oi) {
    float M = fmaxf(m, om);
    float S = s * __expf(m - M) + os * __expf(om - M);
    int I;
    if (m > om)      I = idx;
    else if (om > m) I = oi;
    else             I = (idx < oi) ? idx : oi;
    m = M; s = S; idx = I;
}

// Branchless per-float4 online softmax + argmax update.
__device__ __forceinline__ void proc4(float4 v, int i4,
                                      float& m, float& s, int& idx) {
    const int b = i4 * 4;
    const bool gxy = (v.x >= v.y);
    const float m01 = gxy ? v.x : v.y;
    const int   i01 = gxy ? b : b + 1;
    const bool gzw = (v.z >= v.w);
    const float m23 = gzw ? v.z : v.w;
    const int   i23 = gzw ? b + 2 : b + 3;
    const bool gc  = (m01 >= m23);
    const float cm = gc ? m01 : m23;
    const int   ci = gc ? i01 : i23;

    const float nm = fmaxf(m, cm);
    idx = (cm > m) ? ci : idx;     // strict >: running state is earlier => wins ties

    const float e0 = __expf(v.x - nm);
    const float e1 = __expf(v.y - nm);
    const float e2 = __expf(v.z - nm);
    const float e3 = __expf(v.w - nm);
    s = s * __expf(m - nm) + ((e0 + e1) + (e2 + e3));
    m = nm;
}

// Phase 1: per-row loss -> partial[row]. NO atomics (hypothesis under test:
// 4096 device-scope same-address atomicAdds were a ~200us serialized tail).
// [R2 infra-failed before running; identical resubmission in R3.]
__global__ __launch_bounds__(BLOCK) void focal_loss_kernel(
    const float* __restrict__ input,    // [N, CLS] fp32
    const int*   __restrict__ target,   // [N]
    const float* __restrict__ weight,   // [CLS]
    const float* __restrict__ gammap,   // [1]
    float* __restrict__ partial)        // [N] workspace
{
    const int row = blockIdx.x;
    const size_t base = (size_t)row * CLS;
    const float4* __restrict__ rp4 = (const float4*)(input + base);
    const int tid = threadIdx.x;

    float mA = -FLT_MAX, sA = 0.0f; int iA = 0x7fffffff;
    float mB = -FLT_MAX, sB = 0.0f; int iB = 0x7fffffff;

    int i = tid;
    while (i + BLOCK < NVEC) {
        const float4 a = rp4[i];
        const float4 b = rp4[i + BLOCK];
        proc4(a, i,          mA, sA, iA);
        proc4(b, i + BLOCK,  mB, sB, iB);
        i += 2 * BLOCK;
    }
    if (i < NVEC) proc4(rp4[i], i, mA, sA, iA);

    merge_state(mA, sA, iA, mB, sB, iB);
    float m = mA, s = sA; int idx = iA;

    for (int off = 32; off > 0; off >>= 1) {
        float om = __shfl_down(m, off);
        float os = __shfl_down(s, off);
        int   oi = __shfl_down(idx, off);
        merge_state(m, s, idx, om, os, oi);
    }

    __shared__ float sm[BLOCK / 64];
    __shared__ float ss[BLOCK / 64];
    __shared__ int   si[BLOCK / 64];
    const int wave = tid >> 6;
    if ((tid & 63) == 0) { sm[wave] = m; ss[wave] = s; si[wave] = idx; }
    __syncthreads();

    if (tid == 0) {
        for (int w = 1; w < BLOCK / 64; ++w)
            merge_state(m, s, idx, sm[w], ss[w], si[w]);

        const int   t  = target[row];
        const float xt = input[base + (size_t)t];
        const float logp_t = xt - m - __logf(s);   // log p_target
        const float p_t    = __expf(logp_t);
        const float g      = gammap[0];
        const float w      = weight[idx];          // weight[argmax(input_row)]
        partial[row] = w * __powf(1.0f - p_t, g) * (-logp_t);
    }
}

// Phase 2: sum N partials -> out[0] with a plain store (out is poisoned by
// the harness each iteration; we overwrite it here, so no zero_kernel).
__global__ __launch_bounds__(256) void reduce_kernel(
    const float* __restrict__ partial, float* __restrict__ out, int n)
{
    const int tid = threadIdx.x;
    const float4* __restrict__ p4 = (const float4*)partial;
    float acc = 0.0f;
    for (int i = tid; i < n / 4; i += 256) {
        float4 v = p4[i];
        acc += (v.x + v.y) + (v.z + v.w);
    }
    for (int off = 32; off > 0; off >>= 1)
        acc += __shfl_down(acc, off);

    __shared__ float sacc[4];
    const int wave = tid >> 6;
    if ((tid & 63) == 0) sacc[wave] = acc;
    __syncthreads();
    if (tid == 0)
        out[0] = ((sacc[0] + sacc[1]) + (sacc[2] + sacc[3]));
}

extern "C" void kernel_launch(void* const* d_in, const int* in_sizes, int n_in,
                              void* d_out, int out_size, void* d_ws, size_t ws_size,
                              hipStream_t stream) {
    const float* input  = (const float*)d_in[0];
    const int*   target = (const int*)  d_in[1];
    const float* weight = (const float*)d_in[2];
    const float* gammap = (const float*)d_in[3];
    float* out = (float*)d_out;
    float* partial = (float*)d_ws;      // N floats = 16 KB << ws_size

    const int N = in_sizes[0] / CLS;    // 4096

    focal_loss_kernel<<<N, BLOCK, 0, stream>>>(input, target, weight, gammap, partial);
    reduce_kernel<<<1, 256, 0, stream>>>(partial, out, N);
}